// Round 4
// baseline (82.757 us; speedup 1.0000x reference)
//
#include <hip/hip_runtime.h>
#include <math.h>

#define KS    7
#define PADW  3
#define H     56
#define W     56
#define HW    (H * W)          // 3136
#define TILE  8
#define PATCH 14               // TILE + KS - 1
#define PPOS  (PATCH * PATCH)  // 196 positions, row stride 14 (unpadded: see note)
// float2 row stride 14 -> 112B: the 8 ty-row bank bases {0,28,24,...,4} give each
// bank exactly 4 dwords per 64-lane b64 read = data-minimum cycles, no conflict.

#if __has_builtin(__builtin_amdgcn_exp2f)
#define EXP2F(x) __builtin_amdgcn_exp2f(x)
#else
#define EXP2F(x) exp2f(x)
#endif
#if __has_builtin(__builtin_amdgcn_rcpf)
#define RCPF(x) __builtin_amdgcn_rcpf(x)
#else
#define RCPF(x) (1.0f / (x))
#endif

#define LOG2E 1.44269504088896340736f

__global__ __launch_bounds__(256, 6) void attn_fused(
    const float* __restrict__ x,
    const float* __restrict__ wq,
    const float* __restrict__ wk,
    const float* __restrict__ bk,
    const float* __restrict__ wv,
    const float* __restrict__ bv,
    const float* __restrict__ rel_x,
    const float* __restrict__ rel_y,
    float* __restrict__ out)
{
    __shared__ float2 kvm[8][PPOS];   // (k, v) interleaved: one ds_read_b64 per tap

    const int tid  = threadIdx.x;
    const int tile = blockIdx.x;          // 0..48
    const int bz   = blockIdx.y;          // b*8 + g
    const int b    = bz >> 3;
    const int g    = bz & 7;
    const int c0   = g * 8;

    const int tileY = tile / 7;
    const int tileX = tile - tileY * 7;
    const int h0 = tileY * TILE;
    const int w0 = tileX * TILE;

    const float* wqg = wq + g * 64;       // block-uniform bases -> scalar loads
    const float* wkg = wk + g * 64;
    const float* wvg = wv + g * 64;
    const float* xg  = x + (size_t)(b * 64 + c0) * HW;

    // ---- conv phase: 196 patch positions, one thread each ----
    if (tid < PPOS) {
        const int py = tid / PATCH;
        const int px = tid - py * PATCH;
        const int oy = h0 + py - PADW;
        const int ox = w0 + px - PADW;
        const bool in = (oy >= 0) & (oy < H) & (ox >= 0) & (ox < W);
        const float* xp = xg + oy * W + ox;
        float xv[8];
#pragma unroll
        for (int i = 0; i < 8; ++i)
            xv[i] = in ? xp[i * HW] : 0.f;
#pragma unroll
        for (int dch = 0; dch < 8; ++dch) {
            float ka = bk[c0 + dch];
            float va = bv[c0 + dch];
#pragma unroll
            for (int i = 0; i < 8; ++i) {
                ka = fmaf(xv[i], wkg[dch * 8 + i], ka);
                va = fmaf(xv[i], wvg[dch * 8 + i], va);
            }
            kvm[dch][tid] = make_float2(ka, va);
        }
    }
    __syncthreads();

    // ---- attention: 512 (pixel,dch) tasks, 2 per thread; dch wave-uniform ----
    const int pix  = tid & 63;
    const int dsel = tid >> 6;            // 0..3, uniform per wave
    const int ty   = pix >> 3;
    const int tx   = pix & 7;
    const int h    = h0 + ty;
    const int w    = w0 + tx;

    // center x values (shared by both dch tasks of this thread)
    const float* xcp = xg + h * W + w;
    float xc[8];
#pragma unroll
    for (int i = 0; i < 8; ++i)
        xc[i] = xcp[i * HW];

    const int base = ty * PATCH + tx;

#pragma unroll
    for (int half = 0; half < 2; ++half) {
        const int dch = half * 4 + dsel;  // uniform per wave

        float qv = 0.f;
#pragma unroll
        for (int i = 0; i < 8; ++i)
            qv = fmaf(xc[i], wqg[dch * 8 + i], qv);
        const float qv2 = qv * LOG2E;     // fold log2e: exp(a) = exp2(a*log2e)

        // half==0 -> dch<4: rel_x indexed by window row i
        // half==1 -> dch>=4: rel_y indexed by window col j
        float qvr2[7];
#pragma unroll
        for (int i = 0; i < 7; ++i) {
            float r = (half == 0) ? rel_x[dch * 7 + i]
                                  : rel_y[(dch - 4) * 7 + i];
            qvr2[i] = qv2 * r;
        }

        const float2* kp = &kvm[dch][base];

        float l = 0.f, acc = 0.f;
#pragma unroll
        for (int i = 0; i < 7; ++i) {
            float li = 0.f, ai = 0.f;     // per-row partials: shorter dep chains
#pragma unroll
            for (int j = 0; j < 7; ++j) {
                float2 kv = kp[i * PATCH + j];
                float addv = (half == 0) ? qvr2[i] : qvr2[j];
                float e = EXP2F(fmaf(qv2, kv.x, addv));
                li += e;
                ai = fmaf(e, kv.y, ai);
            }
            l += li;
            acc += ai;
        }

        out[((size_t)(b * 64 + c0 + dch) * H + h) * W + w] = acc * RCPF(l);
    }
}

extern "C" void kernel_launch(void* const* d_in, const int* in_sizes, int n_in,
                              void* d_out, int out_size, void* d_ws, size_t ws_size,
                              hipStream_t stream) {
    const float* x     = (const float*)d_in[0];
    const float* wq    = (const float*)d_in[1];
    const float* wk    = (const float*)d_in[2];
    const float* bk    = (const float*)d_in[3];
    const float* wv    = (const float*)d_in[4];
    const float* bv    = (const float*)d_in[5];
    const float* rel_x = (const float*)d_in[6];
    const float* rel_y = (const float*)d_in[7];

    dim3 grid(49, 32, 1);  // 7x7 tiles of 8x8, b*8+g
    attn_fused<<<grid, dim3(256), 0, stream>>>(
        x, wq, wk, bk, wv, bv, rel_x, rel_y, (float*)d_out);
}